// Round 7
// baseline (15449.214 us; speedup 1.0000x reference)
//
#include <hip/hip_runtime.h>
#include <stdint.h>

// R15 = R12 (verified best, 14.70 ms, absmax=0) + packed-fp32 P2.
// R13 (branch skips) and R14 (dd16) both reverted - measured null/negative.
// P2 rewritten on v_pk_add_f32/v_pk_mul_f32 (CDNA full-rate packed fp32,
// VOP3P): points stored as f32x2 pairs, distance math = 8 pk-ops + 2 scalar
// fmin per pair, halving P2's issue count (~300 -> ~160 insts/thread/step).
// Bit-exact: pk add/mul use the same IEEE-RN rounding as scalar; a-b is
// computed as a+(-b) (exact identity; zero-sign cases vanish under the
// square). Owner select tree = depth-4 over pairs + final .x/.y pick.
// P1/P3'/P4/P5, barriers, staging: R12 verbatim.

namespace {

constexpr int BATCH = 8;
constexpr int NPTS  = 16384;
constexpr int NQ    = 4096;
constexpr int KNN   = 16;
constexpr int BLOCK = 512;            // 8 waves
constexpr int CH    = NPTS / BLOCK;   // 32 points per thread
constexpr int CHP   = CH / 2;         // 16 point-pairs per thread
constexpr int NWAVE = BLOCK / 64;     // 8
constexpr int FLUSH = 256;            // output staging chunk (steps)
constexpr int NCAND = 128;            // candidate buffer cap
constexpr size_t IDX_ELEMS = (size_t)BATCH * NQ * KNN;  // 524288 f32, then pts

typedef float f32x2 __attribute__((ext_vector_type(2)));

__device__ __forceinline__ f32x2 pk_add(f32x2 a, f32x2 b) {
  f32x2 r;
  asm("v_pk_add_f32 %0, %1, %2" : "=v"(r) : "v"(a), "v"(b));
  return r;
}
__device__ __forceinline__ f32x2 pk_mul(f32x2 a, f32x2 b) {
  f32x2 r;
  asm("v_pk_mul_f32 %0, %1, %2" : "=v"(r) : "v"(a), "v"(b));
  return r;
}

// swizzle: insert 1 u32 word of pad per 32 words (2 u16 per 64 u16)
__device__ __forceinline__ int swz32(int v) { return v + (v >> 5); }
__device__ __forceinline__ int swz16(int w) { return w + 2 * (w >> 6); }

// Threefry-2x32, 20 rounds, jax's exact schedule.
__device__ __forceinline__ void tf2x32(uint32_t k0, uint32_t k1,
                                       uint32_t x0, uint32_t x1,
                                       uint32_t &o0, uint32_t &o1) {
  uint32_t ks2 = k0 ^ k1 ^ 0x1BD11BDAu;
  x0 += k0; x1 += k1;
#define TFR(r) { x0 += x1; x1 = (x1 << (r)) | (x1 >> (32 - (r))); x1 ^= x0; }
  TFR(13) TFR(15) TFR(26) TFR(6)
  x0 += k1;  x1 += ks2 + 1u;
  TFR(17) TFR(29) TFR(16) TFR(24)
  x0 += ks2; x1 += k0 + 2u;
  TFR(13) TFR(15) TFR(26) TFR(6)
  x0 += k0;  x1 += k1 + 3u;
  TFR(17) TFR(29) TFR(16) TFR(24)
  x0 += k1;  x1 += ks2 + 4u;
  TFR(13) TFR(15) TFR(26) TFR(6)
  x0 += ks2; x1 += k0 + 5u;
#undef TFR
  o0 = x0; o1 = x1;
}

__device__ __forceinline__ void split_child(uint32_t pk0, uint32_t pk1,
                                            uint32_t i, uint32_t &c0, uint32_t &c1) {
  tf2x32(pk0, pk1, 0u, i, c0, c1);          // partitionable split
}

__device__ __forceinline__ uint32_t bits32_scalar(uint32_t k0, uint32_t k1) {
  uint32_t a0, a1;
  tf2x32(k0, k1, 0u, 0u, a0, a1);
  return a0 ^ a1;                            // partitionable 32-bit draw
}

__device__ __forceinline__ uint32_t jax_randint(uint32_t hi, uint32_t lo, uint32_t span) {
  uint32_t mult = 65536u % span;
  mult = (mult * mult) % span;               // 2^32 % span
  return ((hi % span) * mult + (lo % span)) % span;
}

// n-th (0-based) set bit of m, n < popcount(m)
__device__ __forceinline__ uint32_t nth_set_bit(uint32_t m, uint32_t n) {
  uint32_t pos = 0;
  #pragma unroll
  for (int sh = 16; sh > 0; sh >>= 1) {
    uint32_t c = __popc(m & ((1u << sh) - 1u));
    if (n >= c) { n -= c; m >>= sh; pos += sh; }
  }
  return pos;
}

} // namespace

__global__ __launch_bounds__(BLOCK, 1)
void snn_sample_kernel(const float* __restrict__ xyz, float* __restrict__ out) {
  const int b    = blockIdx.x;
  const int t    = threadIdx.x;
  const int wave = t >> 6;
  const int lane = t & 63;
  const float INF = __int_as_float(0x7f800000);

  __shared__ __align__(16) uint16_t used[16896];        // swizzled, 33792 B
  __shared__ uint32_t mask[NPTS / 32];  // bit j of word w: used[w*32+j]==cur
  __shared__ uint32_t waveSum[NWAVE];   // count per wave's 2048-pt chunk
  __shared__ uint32_t grpSum[64];       // count per 256-pt group
  __shared__ uint32_t pcArr[BLOCK];     // count per thread's 32-pt word
  __shared__ uint32_t wvMin[NWAVE];     // rebuild scratch
  __shared__ float    gmins[64];        // per-8-lane-group min (256 pts each)
  __shared__ unsigned long long cnd[NCAND];
  __shared__ uint32_t rngHi[BLOCK];
  __shared__ uint32_t rngLo[BLOCK];
  __shared__ float    sPt[3];
  __shared__ uint32_t sNc, sCur;
  __shared__ __align__(16) uint16_t idxChunk[FLUSH * KNN];  // 8192 B
  __shared__ __align__(16) float    ptsChunk[FLUSH * 3];    // 3072 B

  // ---- init: points as f32x2 pairs (pair p = points 2p [.x], 2p+1 [.y]) ----
  f32x2 px2[CHP], py2[CHP], pz2[CHP];
  {
    const float* sp = xyz + ((size_t)b * NPTS + (size_t)t * CH) * 3;
    #pragma unroll
    for (int p = 0; p < CHP; ++p) {
      px2[p].x = sp[6 * p + 0]; px2[p].y = sp[6 * p + 3];
      py2[p].x = sp[6 * p + 1]; py2[p].y = sp[6 * p + 4];
      pz2[p].x = sp[6 * p + 2]; pz2[p].y = sp[6 * p + 5];
    }
  }
  {
    uint32_t* u32p = (uint32_t*)used;
    for (int i = t; i < 16896 / 2; i += BLOCK) u32p[i] = 0u;
  }
  mask[t] = 0xFFFFFFFFu;
  pcArr[t] = (uint32_t)CH;                                // 32
  if (t < 64) grpSum[t] = 256u;
  if (t < NWAVE) waveSum[t] = (uint32_t)(NPTS / NWAVE);   // 2048
  if (t == 0) { sNc = 0u; sCur = 0u; }

  uint32_t kb0, kb1;
  split_child(0u, 42u, (uint32_t)b, kb0, kb1);   // batch key of split(key42,8)
  __syncthreads();

  for (int s = 0; s < NQ; ++s) {
    // ---- staged output flush ----------------------------------------------
    if (s != 0 && (s & (FLUSH - 1)) == 0) {
      const int base = s - FLUSH;
      float* po = out + ((size_t)b * NQ + base) * KNN;
      for (int i = t; i < FLUSH * KNN; i += BLOCK) po[i] = (float)idxChunk[i];
      float* pp = out + IDX_ELEMS + ((size_t)b * NQ + base) * 3;
      for (int i = t; i < FLUSH * 3; i += BLOCK) pp[i] = ptsChunk[i];
      __syncthreads();   // new-chunk slot writers run after this barrier
    }

    // ---- rng refill for steps [s, s+512) -----------------------------------
    if ((s & (BLOCK - 1)) == 0) {
      uint32_t ss = (uint32_t)(s + t);
      uint32_t ks0, ks1, u0, u1, v0, v1;
      split_child(kb0, kb1, ss, ks0, ks1);
      split_child(ks0, ks1, 0u, u0, u1);
      split_child(ks0, ks1, 1u, v0, v1);
      rngHi[t] = bits32_scalar(u0, u1);
      rngLo[t] = bits32_scalar(v0, v1);
      __syncthreads();
    }

    // ---- P1: span/r (redundant per thread), flat owner find ----------------
    uint32_t ws[NWAVE];
    uint32_t span = 0;
    #pragma unroll
    for (int w = 0; w < NWAVE; ++w) { ws[w] = waveSum[w]; span += ws[w]; }
    uint32_t cur = sCur;

    if (span == 0u) {                    // rare rebuild: cur advanced
      uint32_t uvals[CH / 2];
      uint32_t mn = 0xFFFFFFFFu;
      const uint32_t* up32 = (const uint32_t*)used;
      #pragma unroll
      for (int j = 0; j < CH / 2; ++j) {
        uint32_t w2 = up32[swz32(t * (CH / 2) + j)];
        uvals[j] = w2;
        uint32_t a = w2 & 0xFFFFu, c = w2 >> 16;
        uint32_t m2 = a < c ? a : c;
        mn = m2 < mn ? m2 : mn;
      }
      #pragma unroll
      for (int m = 1; m < 64; m <<= 1) {
        uint32_t o = (uint32_t)__shfl_xor((int)mn, m, 64);
        mn = o < mn ? o : mn;
      }
      if (lane == 0) wvMin[wave] = mn;
      __syncthreads();
      uint32_t c = wvMin[0];
      #pragma unroll
      for (int w = 1; w < NWAVE; ++w) c = wvMin[w] < c ? wvMin[w] : c;
      cur = c;
      if (t == 0) sCur = c;
      uint32_t mw = 0;
      #pragma unroll
      for (int j = 0; j < CH / 2; ++j) {
        uint32_t w2 = uvals[j];
        if ((w2 & 0xFFFFu) == cur) mw |= 1u << (2 * j);
        if ((w2 >> 16)     == cur) mw |= 1u << (2 * j + 1);
      }
      mask[t] = mw;
      uint32_t pc = __popc(mw);
      pcArr[t] = pc;
      // group sum (8 lanes = 256 pts), then wave sum
      uint32_t acc = pc;
      acc += (uint32_t)__shfl_xor((int)acc, 1, 64);
      acc += (uint32_t)__shfl_xor((int)acc, 2, 64);
      acc += (uint32_t)__shfl_xor((int)acc, 4, 64);
      if ((lane & 7) == 0) grpSum[(wave << 3) + (lane >> 3)] = acc;
      acc += (uint32_t)__shfl_xor((int)acc, 8, 64);
      acc += (uint32_t)__shfl_xor((int)acc, 16, 64);
      acc += (uint32_t)__shfl_xor((int)acc, 32, 64);
      if (lane == 0) waveSum[wave] = acc;
      __syncthreads();
      span = 0;
      #pragma unroll
      for (int w = 0; w < NWAVE; ++w) { ws[w] = waveSum[w]; span += ws[w]; }
    }

    const uint32_t r = jax_randint(rngHi[s & (BLOCK - 1)],
                                   rngLo[s & (BLOCK - 1)], span);
    uint32_t preWave = 0;
    #pragma unroll
    for (int w = 0; w < NWAVE; ++w) preWave += (w < wave) ? ws[w] : 0u;
    if (r >= preWave && r < preWave + ws[wave]) {      // owner wave only
      const int lg = lane >> 3;                        // group in wave
      const int li = lane & 7;                         // index in group
      uint32_t gsv[8];
      #pragma unroll
      for (int g = 0; g < 8; ++g) gsv[g] = grpSum[(wave << 3) + g];
      uint32_t pcv[8];
      #pragma unroll
      for (int u = 0; u < 8; ++u) pcv[u] = pcArr[(wave << 6) + (lg << 3) + u];
      uint32_t base = preWave;
      uint32_t pc = 0;
      #pragma unroll
      for (int g = 0; g < 8; ++g) base += (g < lg) ? gsv[g] : 0u;
      #pragma unroll
      for (int u = 0; u < 8; ++u) {
        base += (u < li) ? pcv[u] : 0u;
        pc = (u == li) ? pcv[u] : pc;
      }
      if (r >= base && r < base + pc) {                // unique owner thread
        uint32_t mw = mask[t];
        uint32_t pos = nth_set_bit(mw, r - base);
        // depth-4 select tree over f32x2 pairs, then final .x/.y pick
        const uint32_t ph = pos >> 1;
        f32x2 sx[8], sy[8], sz[8];
        const bool b3 = (ph & 8u) != 0u;
        #pragma unroll
        for (int i = 0; i < 8; ++i) {
          sx[i] = b3 ? px2[i + 8] : px2[i];
          sy[i] = b3 ? py2[i + 8] : py2[i];
          sz[i] = b3 ? pz2[i + 8] : pz2[i];
        }
        const bool b2 = (ph & 4u) != 0u;
        #pragma unroll
        for (int i = 0; i < 4; ++i) {
          sx[i] = b2 ? sx[i + 4] : sx[i];
          sy[i] = b2 ? sy[i + 4] : sy[i];
          sz[i] = b2 ? sz[i + 4] : sz[i];
        }
        const bool b1 = (ph & 2u) != 0u;
        #pragma unroll
        for (int i = 0; i < 2; ++i) {
          sx[i] = b1 ? sx[i + 2] : sx[i];
          sy[i] = b1 ? sy[i + 2] : sy[i];
          sz[i] = b1 ? sz[i + 2] : sz[i];
        }
        const bool bp = (ph & 1u) != 0u;
        const f32x2 X = bp ? sx[1] : sx[0];
        const f32x2 Y = bp ? sy[1] : sy[0];
        const f32x2 Z = bp ? sz[1] : sz[0];
        const bool blo = (pos & 1u) != 0u;
        const float fx = blo ? X.y : X.x;
        const float fy = blo ? Y.y : Y.x;
        const float fz = blo ? Z.y : Z.x;
        sPt[0] = fx; sPt[1] = fy; sPt[2] = fz;
        float* pb = &ptsChunk[3 * (s & (FLUSH - 1))];  // LDS stage
        pb[0] = fx; pb[1] = fy; pb[2] = fz;
      }
    }
    __syncthreads();                                   // B2
    const float cx = sPt[0], cy = sPt[1], cz = sPt[2];

    // ---- P2: distances via packed fp32 (bit-exact RN) + min tree -----------
    f32x2 ncx, ncy, ncz;
    ncx.x = -cx; ncx.y = -cx;
    ncy.x = -cy; ncy.y = -cy;
    ncz.x = -cz; ncz.y = -cz;
    f32x2 dd2[CHP];
    float m0 = INF, m1 = INF, m2 = INF, m3 = INF;      // 4-way min tree
    #pragma unroll
    for (int p = 0; p < CHP; ++p) {
      f32x2 dx = pk_add(px2[p], ncx);                  // px - cx (a + (-b))
      f32x2 dy = pk_add(py2[p], ncy);
      f32x2 dz = pk_add(pz2[p], ncz);
      f32x2 d  = pk_add(pk_add(pk_mul(dx, dx), pk_mul(dy, dy)),
                        pk_mul(dz, dz));
      dd2[p] = d;
      if (p & 1) { m2 = fminf(m2, d.x); m3 = fminf(m3, d.y); }
      else       { m0 = fminf(m0, d.x); m1 = fminf(m1, d.y); }
    }
    float g = fminf(fminf(m0, m1), fminf(m2, m3));
    // 8-lane-group min (256 points per group)
    g = fminf(g, __shfl_xor(g, 1, 64));
    g = fminf(g, __shfl_xor(g, 2, 64));
    g = fminf(g, __shfl_xor(g, 4, 64));
    if ((lane & 7) == 0) gmins[wave * 8 + (lane >> 3)] = g;
    __syncthreads();                                   // B3

    // ---- P3': per-wave ballot bisection -> thr (no barrier, no serial) -----
    float thr;
    {
      const uint32_t gb = __float_as_uint(gmins[lane]);
      uint32_t T = 0u;
      #pragma unroll
      for (int k = 31; k >= 16; --k) {
        uint32_t cand = T | (1u << k);
        unsigned long long m = __ballot(gb < cand);
        if (__popcll(m) < 16) T = cand;    // wave-uniform branch
      }
      thr = __uint_as_float(T | 0xFFFFu);
    }

    // ---- P4: collect all (d,idx) with d <= thr (superset of true top-16) ---
    #pragma unroll
    for (int p = 0; p < CHP; ++p) {
      if (dd2[p].x <= thr) {
        uint32_t pos = atomicAdd(&sNc, 1u);
        if (pos < (uint32_t)NCAND) {
          cnd[pos] = (((unsigned long long)__float_as_uint(dd2[p].x)) << 32)
                     | (uint32_t)(t * CH + 2 * p);
        }
      }
      if (dd2[p].y <= thr) {
        uint32_t pos = atomicAdd(&sNc, 1u);
        if (pos < (uint32_t)NCAND) {
          cnd[pos] = (((unsigned long long)__float_as_uint(dd2[p].y)) << 32)
                     | (uint32_t)(t * CH + 2 * p + 1);
        }
      }
    }
    __syncthreads();                                   // B5

    // ---- P5: wave 0 ranks candidates (all-pairs, pipelined LDS broadcast) --
    // Keys are distinct u64 (idx unique), so rank = #{c < v} is the exact
    // sorted position; rank 0 is the center (d = 0).
    if (wave == 0) {
      uint32_t nc = sNc; if (nc > (uint32_t)NCAND) nc = (uint32_t)NCAND;
      if (lane >= (int)nc) cnd[lane] = ~0ull;          // sentinels [nc,64)
      unsigned long long v = (lane < (int)nc) ? cnd[lane] : ~0ull;
      const bool big = nc > 64u;                       // wave-uniform, rare
      unsigned long long v2 = ~0ull;
      if (big) {
        if (64 + lane >= (int)nc) cnd[64 + lane] = ~0ull;
        v2 = (64 + lane < (int)nc) ? cnd[64 + lane] : ~0ull;
      }
      const uint32_t ncR = (nc + 7u) & ~7u;
      uint32_t rank = 0;
      for (uint32_t j = 0; j < ncR; j += 8u) {         // independent reads,
        unsigned long long o0 = cnd[j + 0];            // latency pipelined
        unsigned long long o1 = cnd[j + 1];
        unsigned long long o2 = cnd[j + 2];
        unsigned long long o3 = cnd[j + 3];
        unsigned long long o4 = cnd[j + 4];
        unsigned long long o5 = cnd[j + 5];
        unsigned long long o6 = cnd[j + 6];
        unsigned long long o7 = cnd[j + 7];
        rank += (uint32_t)(o0 < v) + (uint32_t)(o1 < v)
              + (uint32_t)(o2 < v) + (uint32_t)(o3 < v)
              + (uint32_t)(o4 < v) + (uint32_t)(o5 < v)
              + (uint32_t)(o6 < v) + (uint32_t)(o7 < v);
      }
      uint32_t rank2 = 0;
      if (big) {
        for (uint32_t j = 0; j < ncR; j += 4u) {
          unsigned long long o0 = cnd[j + 0];
          unsigned long long o1 = cnd[j + 1];
          unsigned long long o2 = cnd[j + 2];
          unsigned long long o3 = cnd[j + 3];
          rank2 += (uint32_t)(o0 < v2) + (uint32_t)(o1 < v2)
                 + (uint32_t)(o2 < v2) + (uint32_t)(o3 < v2);
        }
      }
      if (lane == 0) sNc = 0u;                         // after all reads
      if (lane < (int)nc && rank < (uint32_t)KNN) {
        uint32_t id = (uint32_t)v;
        idxChunk[((s & (FLUSH - 1)) << 4) + rank] = (uint16_t)id;
        int a16 = swz16((int)id);
        uint32_t old = used[a16];
        // rank 0 == center: +1 (neighbor) +100 (center) fused to +101.
        used[a16] = (uint16_t)(old + ((rank == 0u) ? 101u : 1u));
        if (old == cur) {                              // leaves the set
          atomicAnd(&mask[id >> 5], ~(1u << (id & 31u)));
          atomicSub(&waveSum[id >> 11], 1u);
          atomicSub(&grpSum[id >> 8], 1u);
          atomicSub(&pcArr[id >> 5], 1u);
        }
      }
      if (big && 64 + lane < (int)nc && rank2 < (uint32_t)KNN) {
        uint32_t id2 = (uint32_t)v2;
        idxChunk[((s & (FLUSH - 1)) << 4) + rank2] = (uint16_t)id2;
        int a216 = swz16((int)id2);
        uint32_t old2 = used[a216];
        used[a216] = (uint16_t)(old2 + ((rank2 == 0u) ? 101u : 1u));
        if (old2 == cur) {
          atomicAnd(&mask[id2 >> 5], ~(1u << (id2 & 31u)));
          atomicSub(&waveSum[id2 >> 11], 1u);
          atomicSub(&grpSum[id2 >> 8], 1u);
          atomicSub(&pcArr[id2 >> 5], 1u);
        }
      }
    }
    __syncthreads();                                   // B6 (loop top)
  }

  // ---- final flush: last chunk of idx + pts -------------------------------
  {
    const int base = NQ - FLUSH;
    float* po = out + ((size_t)b * NQ + base) * KNN;
    for (int i = t; i < FLUSH * KNN; i += BLOCK) po[i] = (float)idxChunk[i];
    float* pp = out + IDX_ELEMS + ((size_t)b * NQ + base) * 3;
    for (int i = t; i < FLUSH * 3; i += BLOCK) pp[i] = ptsChunk[i];
  }
}

extern "C" void kernel_launch(void* const* d_in, const int* in_sizes, int n_in,
                              void* d_out, int out_size, void* d_ws, size_t ws_size,
                              hipStream_t stream) {
  (void)in_sizes; (void)n_in; (void)d_ws; (void)ws_size; (void)out_size;
  const float* xyz = (const float*)d_in[0];
  float* out = (float*)d_out;
  snn_sample_kernel<<<dim3(BATCH), dim3(BLOCK), 0, stream>>>(xyz, out);
}

// Round 8
// 14186.163 us; speedup vs baseline: 1.0890x; 1.0890x over previous
//
#include <hip/hip_runtime.h>
#include <stdint.h>

// R16 = R12 (verified best, 14.70 ms, absmax=0) + idle-wave RNG precompute.
// R13/R14/R15 all reverted (measured null/negative). Model: step time is
// serial chains + barriers; parallel VALU is hidden (R15: -14% insts, +5%
// time). This round removes the longest remaining serial chain in P1:
//  - jax_randint = 5 dependent u32 mods (~300-400 cyc) on the B6->B2 path.
//    Span shrinks by k in [1,32] per step, so during P5 (where only wave 0
//    works) wave 1 lanes 0..32 precompute rTab[k] = randint(hi_next,
//    lo_next, span-k) for every possible next span. P1 then reads
//    r = rTab[spanPrev - span] (one broadcast LDS read). Bit-exact: same
//    hi/lo (refill boundary: wave 1 runs the threefry directly = same bits),
//    same span. Rebuild steps and s==0 use the inline randint (rare).
//  - gsv/pcv LDS loads hoisted above the r-dependent owner test (~150 cyc
//    off the owner wave's post-r chain; loads are exec-unconditional).
// Everything else byte-identical to R12.

namespace {

constexpr int BATCH = 8;
constexpr int NPTS  = 16384;
constexpr int NQ    = 4096;
constexpr int KNN   = 16;
constexpr int BLOCK = 512;            // 8 waves
constexpr int CH    = NPTS / BLOCK;   // 32 points per thread
constexpr int NWAVE = BLOCK / 64;     // 8
constexpr int FLUSH = 256;            // output staging chunk (steps)
constexpr int NCAND = 128;            // candidate buffer cap
constexpr size_t IDX_ELEMS = (size_t)BATCH * NQ * KNN;  // 524288 f32, then pts

// swizzle: insert 1 u32 word of pad per 32 words (2 u16 per 64 u16)
__device__ __forceinline__ int swz32(int v) { return v + (v >> 5); }
__device__ __forceinline__ int swz16(int w) { return w + 2 * (w >> 6); }

// Threefry-2x32, 20 rounds, jax's exact schedule.
__device__ __forceinline__ void tf2x32(uint32_t k0, uint32_t k1,
                                       uint32_t x0, uint32_t x1,
                                       uint32_t &o0, uint32_t &o1) {
  uint32_t ks2 = k0 ^ k1 ^ 0x1BD11BDAu;
  x0 += k0; x1 += k1;
#define TFR(r) { x0 += x1; x1 = (x1 << (r)) | (x1 >> (32 - (r))); x1 ^= x0; }
  TFR(13) TFR(15) TFR(26) TFR(6)
  x0 += k1;  x1 += ks2 + 1u;
  TFR(17) TFR(29) TFR(16) TFR(24)
  x0 += ks2; x1 += k0 + 2u;
  TFR(13) TFR(15) TFR(26) TFR(6)
  x0 += k0;  x1 += k1 + 3u;
  TFR(17) TFR(29) TFR(16) TFR(24)
  x0 += k1;  x1 += ks2 + 4u;
  TFR(13) TFR(15) TFR(26) TFR(6)
  x0 += ks2; x1 += k0 + 5u;
#undef TFR
  o0 = x0; o1 = x1;
}

__device__ __forceinline__ void split_child(uint32_t pk0, uint32_t pk1,
                                            uint32_t i, uint32_t &c0, uint32_t &c1) {
  tf2x32(pk0, pk1, 0u, i, c0, c1);          // partitionable split
}

__device__ __forceinline__ uint32_t bits32_scalar(uint32_t k0, uint32_t k1) {
  uint32_t a0, a1;
  tf2x32(k0, k1, 0u, 0u, a0, a1);
  return a0 ^ a1;                            // partitionable 32-bit draw
}

__device__ __forceinline__ uint32_t jax_randint(uint32_t hi, uint32_t lo, uint32_t span) {
  uint32_t mult = 65536u % span;
  mult = (mult * mult) % span;               // 2^32 % span
  return ((hi % span) * mult + (lo % span)) % span;
}

// n-th (0-based) set bit of m, n < popcount(m)
__device__ __forceinline__ uint32_t nth_set_bit(uint32_t m, uint32_t n) {
  uint32_t pos = 0;
  #pragma unroll
  for (int sh = 16; sh > 0; sh >>= 1) {
    uint32_t c = __popc(m & ((1u << sh) - 1u));
    if (n >= c) { n -= c; m >>= sh; pos += sh; }
  }
  return pos;
}

} // namespace

__global__ __launch_bounds__(BLOCK, 1)
void snn_sample_kernel(const float* __restrict__ xyz, float* __restrict__ out) {
  const int b    = blockIdx.x;
  const int t    = threadIdx.x;
  const int wave = t >> 6;
  const int lane = t & 63;
  const float INF = __int_as_float(0x7f800000);

  __shared__ __align__(16) uint16_t used[16896];        // swizzled, 33792 B
  __shared__ uint32_t mask[NPTS / 32];  // bit j of word w: used[w*32+j]==cur
  __shared__ uint32_t waveSum[NWAVE];   // count per wave's 2048-pt chunk
  __shared__ uint32_t grpSum[64];       // count per 256-pt group
  __shared__ uint32_t pcArr[BLOCK];     // count per thread's 32-pt word
  __shared__ uint32_t wvMin[NWAVE];     // rebuild scratch
  __shared__ float    gmins[64];        // per-8-lane-group min (256 pts each)
  __shared__ unsigned long long cnd[NCAND];
  __shared__ uint32_t rngHi[BLOCK];
  __shared__ uint32_t rngLo[BLOCK];
  __shared__ uint32_t rTab[33];         // precomputed randint per span delta
  __shared__ float    sPt[3];
  __shared__ uint32_t sNc, sCur;
  __shared__ __align__(16) uint16_t idxChunk[FLUSH * KNN];  // 8192 B
  __shared__ __align__(16) float    ptsChunk[FLUSH * 3];    // 3072 B

  // ---- init --------------------------------------------------------------
  float px[CH], py[CH], pz[CH];
  {
    const float* sp = xyz + ((size_t)b * NPTS + (size_t)t * CH) * 3;
    #pragma unroll
    for (int j = 0; j < CH; ++j) {
      px[j] = sp[3 * j + 0];
      py[j] = sp[3 * j + 1];
      pz[j] = sp[3 * j + 2];
    }
  }
  {
    uint32_t* u32p = (uint32_t*)used;
    for (int i = t; i < 16896 / 2; i += BLOCK) u32p[i] = 0u;
  }
  mask[t] = 0xFFFFFFFFu;
  pcArr[t] = (uint32_t)CH;                                // 32
  if (t < 64) grpSum[t] = 256u;
  if (t < NWAVE) waveSum[t] = (uint32_t)(NPTS / NWAVE);   // 2048
  if (t == 0) { sNc = 0u; sCur = 0u; }

  uint32_t kb0, kb1;
  split_child(0u, 42u, (uint32_t)b, kb0, kb1);   // batch key of split(key42,8)
  uint32_t spanPrev = 0u;                        // last step's span (register)
  __syncthreads();

  for (int s = 0; s < NQ; ++s) {
    // ---- staged output flush ----------------------------------------------
    if (s != 0 && (s & (FLUSH - 1)) == 0) {
      const int base = s - FLUSH;
      float* po = out + ((size_t)b * NQ + base) * KNN;
      for (int i = t; i < FLUSH * KNN; i += BLOCK) po[i] = (float)idxChunk[i];
      float* pp = out + IDX_ELEMS + ((size_t)b * NQ + base) * 3;
      for (int i = t; i < FLUSH * 3; i += BLOCK) pp[i] = ptsChunk[i];
      __syncthreads();   // new-chunk slot writers run after this barrier
    }

    // ---- rng refill for steps [s, s+512) -----------------------------------
    if ((s & (BLOCK - 1)) == 0) {
      uint32_t ss = (uint32_t)(s + t);
      uint32_t ks0, ks1, u0, u1, v0, v1;
      split_child(kb0, kb1, ss, ks0, ks1);
      split_child(ks0, ks1, 0u, u0, u1);
      split_child(ks0, ks1, 1u, v0, v1);
      rngHi[t] = bits32_scalar(u0, u1);
      rngLo[t] = bits32_scalar(v0, v1);
      __syncthreads();
    }

    // ---- P1: span/r (redundant per thread), flat owner find ----------------
    uint32_t ws[NWAVE];
    uint32_t span = 0;
    #pragma unroll
    for (int w = 0; w < NWAVE; ++w) { ws[w] = waveSum[w]; span += ws[w]; }
    uint32_t cur = sCur;
    bool fresh = false;                  // true when rTab is not applicable

    if (span == 0u) {                    // rare rebuild: cur advanced
      fresh = true;
      uint32_t uvals[CH / 2];
      uint32_t mn = 0xFFFFFFFFu;
      const uint32_t* up32 = (const uint32_t*)used;
      #pragma unroll
      for (int j = 0; j < CH / 2; ++j) {
        uint32_t w2 = up32[swz32(t * (CH / 2) + j)];
        uvals[j] = w2;
        uint32_t a = w2 & 0xFFFFu, c = w2 >> 16;
        uint32_t m2 = a < c ? a : c;
        mn = m2 < mn ? m2 : mn;
      }
      #pragma unroll
      for (int m = 1; m < 64; m <<= 1) {
        uint32_t o = (uint32_t)__shfl_xor((int)mn, m, 64);
        mn = o < mn ? o : mn;
      }
      if (lane == 0) wvMin[wave] = mn;
      __syncthreads();
      uint32_t c = wvMin[0];
      #pragma unroll
      for (int w = 1; w < NWAVE; ++w) c = wvMin[w] < c ? wvMin[w] : c;
      cur = c;
      if (t == 0) sCur = c;
      uint32_t mw = 0;
      #pragma unroll
      for (int j = 0; j < CH / 2; ++j) {
        uint32_t w2 = uvals[j];
        if ((w2 & 0xFFFFu) == cur) mw |= 1u << (2 * j);
        if ((w2 >> 16)     == cur) mw |= 1u << (2 * j + 1);
      }
      mask[t] = mw;
      uint32_t pc = __popc(mw);
      pcArr[t] = pc;
      // group sum (8 lanes = 256 pts), then wave sum
      uint32_t acc = pc;
      acc += (uint32_t)__shfl_xor((int)acc, 1, 64);
      acc += (uint32_t)__shfl_xor((int)acc, 2, 64);
      acc += (uint32_t)__shfl_xor((int)acc, 4, 64);
      if ((lane & 7) == 0) grpSum[(wave << 3) + (lane >> 3)] = acc;
      acc += (uint32_t)__shfl_xor((int)acc, 8, 64);
      acc += (uint32_t)__shfl_xor((int)acc, 16, 64);
      acc += (uint32_t)__shfl_xor((int)acc, 32, 64);
      if (lane == 0) waveSum[wave] = acc;
      __syncthreads();
      span = 0;
      #pragma unroll
      for (int w = 0; w < NWAVE; ++w) { ws[w] = waveSum[w]; span += ws[w]; }
    }

    // r: precomputed by wave 1 last step (steady), inline on s==0/rebuild.
    uint32_t r;
    if (s == 0 || fresh) {
      r = jax_randint(rngHi[s & (BLOCK - 1)], rngLo[s & (BLOCK - 1)], span);
    } else {
      r = rTab[spanPrev - span];         // bit-identical by construction
    }
    spanPrev = span;

    uint32_t preWave = 0;
    #pragma unroll
    for (int w = 0; w < NWAVE; ++w) preWave += (w < wave) ? ws[w] : 0u;
    // hoisted: group/thread count loads (independent of r)
    const int lg = lane >> 3;                        // group in wave
    const int li = lane & 7;                         // index in group
    uint32_t gsv[8];
    #pragma unroll
    for (int g2 = 0; g2 < 8; ++g2) gsv[g2] = grpSum[(wave << 3) + g2];
    uint32_t pcv[8];
    #pragma unroll
    for (int u = 0; u < 8; ++u) pcv[u] = pcArr[(wave << 6) + (lg << 3) + u];
    if (r >= preWave && r < preWave + ws[wave]) {      // owner wave only
      uint32_t base = preWave;
      uint32_t pc = 0;
      #pragma unroll
      for (int g2 = 0; g2 < 8; ++g2) base += (g2 < lg) ? gsv[g2] : 0u;
      #pragma unroll
      for (int u = 0; u < 8; ++u) {
        base += (u < li) ? pcv[u] : 0u;
        pc = (u == li) ? pcv[u] : pc;
      }
      if (r >= base && r < base + pc) {                // unique owner thread
        uint32_t mw = mask[t];
        uint32_t pos = nth_set_bit(mw, r - base);
        // depth-5 select tree over own registers (chain 5, not 31)
        float sx[16], sy[16], sz[16];
        const bool b4 = (pos & 16u) != 0u;
        #pragma unroll
        for (int i = 0; i < 16; ++i) {
          sx[i] = b4 ? px[i + 16] : px[i];
          sy[i] = b4 ? py[i + 16] : py[i];
          sz[i] = b4 ? pz[i + 16] : pz[i];
        }
        const bool b3 = (pos & 8u) != 0u;
        #pragma unroll
        for (int i = 0; i < 8; ++i) {
          sx[i] = b3 ? sx[i + 8] : sx[i];
          sy[i] = b3 ? sy[i + 8] : sy[i];
          sz[i] = b3 ? sz[i + 8] : sz[i];
        }
        const bool b2 = (pos & 4u) != 0u;
        #pragma unroll
        for (int i = 0; i < 4; ++i) {
          sx[i] = b2 ? sx[i + 4] : sx[i];
          sy[i] = b2 ? sy[i + 4] : sy[i];
          sz[i] = b2 ? sz[i + 4] : sz[i];
        }
        const bool b1 = (pos & 2u) != 0u;
        #pragma unroll
        for (int i = 0; i < 2; ++i) {
          sx[i] = b1 ? sx[i + 2] : sx[i];
          sy[i] = b1 ? sy[i + 2] : sy[i];
          sz[i] = b1 ? sz[i + 2] : sz[i];
        }
        const bool b0 = (pos & 1u) != 0u;
        const float fx = b0 ? sx[1] : sx[0];
        const float fy = b0 ? sy[1] : sy[0];
        const float fz = b0 ? sz[1] : sz[0];
        sPt[0] = fx; sPt[1] = fy; sPt[2] = fz;
        float* pb = &ptsChunk[3 * (s & (FLUSH - 1))];  // LDS stage
        pb[0] = fx; pb[1] = fy; pb[2] = fz;
      }
    }
    __syncthreads();                                   // B2
    const float cx = sPt[0], cy = sPt[1], cz = sPt[2];

    // ---- P2: distances (strict RN, no FMA) + thread-min + group-min --------
    float dd[CH];
    float m0 = INF, m1 = INF, m2 = INF, m3 = INF;      // 4-way min tree
    #pragma unroll
    for (int j = 0; j < CH; j += 4) {
      #pragma unroll
      for (int q = 0; q < 4; ++q) {
        float dx = __fsub_rn(px[j + q], cx);
        float dy = __fsub_rn(py[j + q], cy);
        float dz = __fsub_rn(pz[j + q], cz);
        dd[j + q] = __fadd_rn(__fadd_rn(__fmul_rn(dx, dx), __fmul_rn(dy, dy)),
                              __fmul_rn(dz, dz));
      }
      m0 = fminf(m0, dd[j + 0]);
      m1 = fminf(m1, dd[j + 1]);
      m2 = fminf(m2, dd[j + 2]);
      m3 = fminf(m3, dd[j + 3]);
    }
    float g = fminf(fminf(m0, m1), fminf(m2, m3));
    // 8-lane-group min (256 points per group)
    g = fminf(g, __shfl_xor(g, 1, 64));
    g = fminf(g, __shfl_xor(g, 2, 64));
    g = fminf(g, __shfl_xor(g, 4, 64));
    if ((lane & 7) == 0) gmins[wave * 8 + (lane >> 3)] = g;
    __syncthreads();                                   // B3

    // ---- P3': per-wave ballot bisection -> thr (no barrier, no serial) -----
    float thr;
    {
      const uint32_t gb = __float_as_uint(gmins[lane]);
      uint32_t T = 0u;
      #pragma unroll
      for (int k = 31; k >= 16; --k) {
        uint32_t cand = T | (1u << k);
        unsigned long long m = __ballot(gb < cand);
        if (__popcll(m) < 16) T = cand;    // wave-uniform branch
      }
      thr = __uint_as_float(T | 0xFFFFu);
    }

    // ---- P4: collect all (d,idx) with d <= thr (superset of true top-16) ---
    #pragma unroll
    for (int j = 0; j < CH; ++j) {
      if (dd[j] <= thr) {
        uint32_t pos = atomicAdd(&sNc, 1u);
        if (pos < (uint32_t)NCAND) {
          cnd[pos] = (((unsigned long long)__float_as_uint(dd[j])) << 32)
                     | (uint32_t)(t * CH + j);
        }
      }
    }
    __syncthreads();                                   // B5

    // ---- P5: wave 0 ranks candidates; wave 1 precomputes next-step r -------
    if (wave == 0) {
      uint32_t nc = sNc; if (nc > (uint32_t)NCAND) nc = (uint32_t)NCAND;
      if (lane >= (int)nc) cnd[lane] = ~0ull;          // sentinels [nc,64)
      unsigned long long v = (lane < (int)nc) ? cnd[lane] : ~0ull;
      const bool big = nc > 64u;                       // wave-uniform, rare
      unsigned long long v2 = ~0ull;
      if (big) {
        if (64 + lane >= (int)nc) cnd[64 + lane] = ~0ull;
        v2 = (64 + lane < (int)nc) ? cnd[64 + lane] : ~0ull;
      }
      const uint32_t ncR = (nc + 7u) & ~7u;
      uint32_t rank = 0;
      for (uint32_t j = 0; j < ncR; j += 8u) {         // independent reads,
        unsigned long long o0 = cnd[j + 0];            // latency pipelined
        unsigned long long o1 = cnd[j + 1];
        unsigned long long o2 = cnd[j + 2];
        unsigned long long o3 = cnd[j + 3];
        unsigned long long o4 = cnd[j + 4];
        unsigned long long o5 = cnd[j + 5];
        unsigned long long o6 = cnd[j + 6];
        unsigned long long o7 = cnd[j + 7];
        rank += (uint32_t)(o0 < v) + (uint32_t)(o1 < v)
              + (uint32_t)(o2 < v) + (uint32_t)(o3 < v)
              + (uint32_t)(o4 < v) + (uint32_t)(o5 < v)
              + (uint32_t)(o6 < v) + (uint32_t)(o7 < v);
      }
      uint32_t rank2 = 0;
      if (big) {
        for (uint32_t j = 0; j < ncR; j += 4u) {
          unsigned long long o0 = cnd[j + 0];
          unsigned long long o1 = cnd[j + 1];
          unsigned long long o2 = cnd[j + 2];
          unsigned long long o3 = cnd[j + 3];
          rank2 += (uint32_t)(o0 < v2) + (uint32_t)(o1 < v2)
                 + (uint32_t)(o2 < v2) + (uint32_t)(o3 < v2);
        }
      }
      if (lane == 0) sNc = 0u;                         // after all reads
      if (lane < (int)nc && rank < (uint32_t)KNN) {
        uint32_t id = (uint32_t)v;
        idxChunk[((s & (FLUSH - 1)) << 4) + rank] = (uint16_t)id;
        int a16 = swz16((int)id);
        uint32_t old = used[a16];
        // rank 0 == center: +1 (neighbor) +100 (center) fused to +101.
        used[a16] = (uint16_t)(old + ((rank == 0u) ? 101u : 1u));
        if (old == cur) {                              // leaves the set
          atomicAnd(&mask[id >> 5], ~(1u << (id & 31u)));
          atomicSub(&waveSum[id >> 11], 1u);
          atomicSub(&grpSum[id >> 8], 1u);
          atomicSub(&pcArr[id >> 5], 1u);
        }
      }
      if (big && 64 + lane < (int)nc && rank2 < (uint32_t)KNN) {
        uint32_t id2 = (uint32_t)v2;
        idxChunk[((s & (FLUSH - 1)) << 4) + rank2] = (uint16_t)id2;
        int a216 = swz16((int)id2);
        uint32_t old2 = used[a216];
        used[a216] = (uint16_t)(old2 + ((rank2 == 0u) ? 101u : 1u));
        if (old2 == cur) {
          atomicAnd(&mask[id2 >> 5], ~(1u << (id2 & 31u)));
          atomicSub(&waveSum[id2 >> 11], 1u);
          atomicSub(&grpSum[id2 >> 8], 1u);
          atomicSub(&pcArr[id2 >> 5], 1u);
        }
      }
    } else if (wave == 1 && lane < 33) {
      // next-step r for every possible span_next = span - k, k in [0,32].
      // Runs entirely inside P5's window (wave 1 was idle). Bit-identical:
      // same hi/lo bits as the table/refill, same span value.
      uint32_t sn = span - (uint32_t)lane;
      if (sn != 0u && sn <= (uint32_t)NPTS) {          // skip invalid spans
        uint32_t nhi, nlo;
        if (((s + 1) & (BLOCK - 1)) == 0) {            // refill boundary:
          uint32_t ss = (uint32_t)(s + 1);             // compute bits directly
          uint32_t ks0, ks1, u0, u1, v0, v1;
          split_child(kb0, kb1, ss, ks0, ks1);
          split_child(ks0, ks1, 0u, u0, u1);
          split_child(ks0, ks1, 1u, v0, v1);
          nhi = bits32_scalar(u0, u1);
          nlo = bits32_scalar(v0, v1);
        } else {
          nhi = rngHi[(s + 1) & (BLOCK - 1)];
          nlo = rngLo[(s + 1) & (BLOCK - 1)];
        }
        rTab[lane] = jax_randint(nhi, nlo, sn);
      }
    }
    __syncthreads();                                   // B6 (loop top)
  }

  // ---- final flush: last chunk of idx + pts -------------------------------
  {
    const int base = NQ - FLUSH;
    float* po = out + ((size_t)b * NQ + base) * KNN;
    for (int i = t; i < FLUSH * KNN; i += BLOCK) po[i] = (float)idxChunk[i];
    float* pp = out + IDX_ELEMS + ((size_t)b * NQ + base) * 3;
    for (int i = t; i < FLUSH * 3; i += BLOCK) pp[i] = ptsChunk[i];
  }
}

extern "C" void kernel_launch(void* const* d_in, const int* in_sizes, int n_in,
                              void* d_out, int out_size, void* d_ws, size_t ws_size,
                              hipStream_t stream) {
  (void)in_sizes; (void)n_in; (void)d_ws; (void)ws_size; (void)out_size;
  const float* xyz = (const float*)d_in[0];
  float* out = (float*)d_out;
  snn_sample_kernel<<<dim3(BATCH), dim3(BLOCK), 0, stream>>>(xyz, out);
}